// Round 1
// baseline (1073.829 us; speedup 1.0000x reference)
//
#include <hip/hip_runtime.h>
#include <stdint.h>

#define NE 8192
#define KD 512
#define MT 65536

typedef __attribute__((ext_vector_type(8))) short bf16x8;
typedef __attribute__((ext_vector_type(4))) float f32x4;

union U128 { uint4 u; bf16x8 b; };

// ---- workspace layout (bytes) ----
#define WS_SUMZ2   0                  // float
#define WS_SUMSMIN 4                  // float
#define WS_HIST    8                  // 8192 * int
#define WS_ZEROSZ  40960              // memset region covers the above
#define WS_E2      40960              // 8192 floats
#define WS_IDX     73728              // 65536 ints
#define WS_EMB16   335872             // 8192*512 bf16 (ushort)
#define WS_Z16     8724480            // 65536*512 bf16 (ushort)
// total ws needed: 75,833,344 bytes

__device__ __forceinline__ unsigned int f2bf(float f) {
    union { float f; unsigned int u; } c; c.f = f;
    return (c.u + 0x7FFFu + ((c.u >> 16) & 1u)) >> 16;
}

__device__ __forceinline__ void load_lds16(const void* g, void* l) {
    __builtin_amdgcn_global_load_lds((const __attribute__((address_space(1))) void*)g,
                                     (__attribute__((address_space(3))) void*)l,
                                     16, 0, 0);
}

// ---------------- K0: emb -> bf16, e2 = ||e||^2 ----------------
__global__ void k_embprep(const float* __restrict__ emb,
                          unsigned short* __restrict__ emb16,
                          float* __restrict__ e2) {
    const int code = blockIdx.x;
    const int lane = threadIdx.x;  // 64
    const float4* row = (const float4*)(emb + (size_t)code * KD);
    float4 a = row[lane * 2];
    float4 b = row[lane * 2 + 1];
    float s = a.x*a.x + a.y*a.y + a.z*a.z + a.w*a.w
            + b.x*b.x + b.y*b.y + b.z*b.z + b.w*b.w;
    uint4 o;
    o.x = f2bf(a.x) | (f2bf(a.y) << 16);
    o.y = f2bf(a.z) | (f2bf(a.w) << 16);
    o.z = f2bf(b.x) | (f2bf(b.y) << 16);
    o.w = f2bf(b.z) | (f2bf(b.w) << 16);
    ((uint4*)(emb16 + (size_t)code * KD))[lane] = o;
    #pragma unroll
    for (int off = 32; off; off >>= 1) s += __shfl_down(s, off, 64);
    if (lane == 0) e2[code] = s;
}

// ---------------- K1: transpose z (N,C,T) -> z16[M][K] bf16, sum z^2 ----------------
__global__ void k_zprep(const float* __restrict__ z,
                        unsigned short* __restrict__ z16,
                        float* __restrict__ sumz2) {
    // grid: (32 t-tiles, 16 c-tiles, 32 n); 256 threads
    const int tx = threadIdx.x & 63;
    const int cu = threadIdx.x >> 6;       // 0..3
    const int n  = blockIdx.z;
    const int c0 = blockIdx.y * 32 + cu * 8;
    const int t  = blockIdx.x * 64 + tx;
    const float* base = z + ((size_t)n * KD) * 2048 + t;
    float v[8]; float s = 0.f;
    #pragma unroll
    for (int u = 0; u < 8; u++) {
        v[u] = base[(size_t)(c0 + u) * 2048];
        s += v[u] * v[u];
    }
    uint4 o;
    o.x = f2bf(v[0]) | (f2bf(v[1]) << 16);
    o.y = f2bf(v[2]) | (f2bf(v[3]) << 16);
    o.z = f2bf(v[4]) | (f2bf(v[5]) << 16);
    o.w = f2bf(v[6]) | (f2bf(v[7]) << 16);
    *(uint4*)(z16 + ((size_t)(n * 2048 + t)) * KD + c0) = o;

    #pragma unroll
    for (int off = 32; off; off >>= 1) s += __shfl_down(s, off, 64);
    __shared__ float red[4];
    if ((threadIdx.x & 63) == 0) red[threadIdx.x >> 6] = s;
    __syncthreads();
    if (threadIdx.x == 0) atomicAdd(sumz2, red[0] + red[1] + red[2] + red[3]);
}

// ---------------- K2: fused GEMM + argmin ----------------
__global__ __launch_bounds__(512, 2) void k_main(
    const unsigned short* __restrict__ z16,   // [65536][512]
    const unsigned short* __restrict__ emb16, // [8192][512]
    const float* __restrict__ e2,             // [8192]
    int* __restrict__ g_idx,                  // [65536]
    int* __restrict__ hist,                   // [8192]
    float* __restrict__ sums)                 // ws base: [0]=sumz2, [1]=sumsmin
{
    __shared__ __align__(16) unsigned short zt[128 * 512];   // 131072 B, swizzled
    __shared__ __align__(16) unsigned short et[2][256 * 32]; // 32768 B

    const int tid  = threadIdx.x;
    const int lane = tid & 63;
    const int w    = tid >> 6;       // 0..7
    const int wm   = w & 1;
    const int wn   = w >> 1;         // 0..3
    const int quad = lane >> 4;
    const int col  = lane & 15;
    const int m0   = blockIdx.x * 128;

    // ---- stage zt: rows m0..m0+127, full K, 16B-chunk XOR swizzle ----
    {
        const int r  = tid >> 2;             // 0..127
        const int jb = (tid & 3) << 4;       // 0,16,32,48
        const uint4* gz = (const uint4*)(z16 + (size_t)(m0 + r) * KD);
        uint4* zt4w = (uint4*)zt;
        #pragma unroll
        for (int jj = 0; jj < 16; jj++) {
            int j  = jb + jj;
            int js = (j & 56) | ((j ^ r) & 7);
            zt4w[r * 64 + js] = gz[j];
        }
    }

    // staging address precompute (per thread, 2 insts of 16B per step)
    const int st_nl0 = w * 16 + (lane >> 2);        // row within 128-half
    const int st_q8  = (lane & 3) * 8;              // quarter offset (elems)
    unsigned short* st_l0 = &et[0][0] + w * 512 + lane * 8;           // p=0
    unsigned short* st_l1 = &et[0][0] + 4096 + w * 512 + lane * 8;    // p=1

    f32x4 acc[4][4];
    #pragma unroll
    for (int mf = 0; mf < 4; mf++)
        #pragma unroll
        for (int nf = 0; nf < 4; nf++)
            acc[mf][nf] = (f32x4){0.f, 0.f, 0.f, 0.f};

    float rbv[4][4]; int rbi[4][4];
    #pragma unroll
    for (int mf = 0; mf < 4; mf++)
        #pragma unroll
        for (int rg = 0; rg < 4; rg++) { rbv[mf][rg] = 3.0e38f; rbi[mf][rg] = 0; }

    // A-read precompute
    int zbase[4], r7[4];
    #pragma unroll
    for (int mf = 0; mf < 4; mf++) {
        int r = wm * 64 + mf * 16 + col;
        zbase[mf] = r * 64;
        r7[mf] = r & 7;
    }
    // B-read precompute (step-invariant uint4 indices within a buffer)
    int bidx[4];
    #pragma unroll
    for (int nf = 0; nf < 4; nf++)
        bidx[nf] = (wn * 64 + nf * 16 + col) * 4 + quad;

    const uint4* zt4 = (const uint4*)zt;
    const uint4* et4[2] = { (const uint4*)&et[0][0], (const uint4*)&et[1][0] };

    // prologue: stage step 0 (chunk 0, kk 0 -> buf 0)
    {
        const unsigned short* g0 = emb16 + ((size_t)(st_nl0) << 9) + st_q8;
        const unsigned short* g1 = emb16 + ((size_t)(128 + st_nl0) << 9) + st_q8;
        load_lds16(g0, st_l0);
        load_lds16(g1, st_l1);
    }

    #pragma unroll 1
    for (int chunk = 0; chunk < 32; chunk++) {
        #pragma unroll
        for (int kk = 0; kk < 16; kk++) {
            __syncthreads();   // drains vmcnt: buf(kk&1) staged; prev reads of buf((kk+1)&1) done
            // prefetch next step into the other buffer
            const int nxt = chunk * 16 + kk + 1;
            if (nxt < 512) {
                const int nchunk = nxt >> 4, nkk = nxt & 15, nbuf = nxt & 1;
                const size_t koff = (size_t)nkk * 32 + st_q8;
                const unsigned short* g0 = emb16 + (((size_t)(nchunk * 256 + st_nl0)) << 9) + koff;
                const unsigned short* g1 = emb16 + (((size_t)(nchunk * 256 + 128 + st_nl0)) << 9) + koff;
                load_lds16(g0, st_l0 + nbuf * 8192);
                load_lds16(g1, st_l1 + nbuf * 8192);
            }
            const int buf = kk & 1;
            const int jhi  = (kk * 4) & 56;
            const int jlow = ((kk & 1) << 2) | quad;
            bf16x8 af[4], bfv[4];
            #pragma unroll
            for (int mf = 0; mf < 4; mf++) {
                U128 u; u.u = zt4[zbase[mf] + (jhi | (jlow ^ r7[mf]))];
                af[mf] = u.b;
            }
            #pragma unroll
            for (int nf = 0; nf < 4; nf++) {
                U128 u; u.u = et4[buf][bidx[nf]];
                bfv[nf] = u.b;
            }
            #pragma unroll
            for (int mf = 0; mf < 4; mf++)
                #pragma unroll
                for (int nf = 0; nf < 4; nf++)
                    acc[mf][nf] = __builtin_amdgcn_mfma_f32_16x16x32_bf16(
                        af[mf], bfv[nf], acc[mf][nf], 0, 0, 0);
        }
        // ---- epilogue: s = e2 - 2*dot, running argmin ----
        const int nb = chunk * 256 + wn * 64 + col;
        float e2v[4];
        #pragma unroll
        for (int nf = 0; nf < 4; nf++) e2v[nf] = e2[nb + nf * 16];
        #pragma unroll
        for (int mf = 0; mf < 4; mf++) {
            #pragma unroll
            for (int rg = 0; rg < 4; rg++) {
                float v0 = fmaf(-2.f, acc[mf][0][rg], e2v[0]);
                float v1 = fmaf(-2.f, acc[mf][1][rg], e2v[1]);
                float v2 = fmaf(-2.f, acc[mf][2][rg], e2v[2]);
                float v3 = fmaf(-2.f, acc[mf][3][rg], e2v[3]);
                float bv = v0; int bn = 0;
                if (v1 < bv) { bv = v1; bn = 1; }
                if (v2 < bv) { bv = v2; bn = 2; }
                if (v3 < bv) { bv = v3; bn = 3; }
                if (bv < rbv[mf][rg]) { rbv[mf][rg] = bv; rbi[mf][rg] = nb + (bn << 4); }
            }
            #pragma unroll
            for (int nf = 0; nf < 4; nf++)
                acc[mf][nf] = (f32x4){0.f, 0.f, 0.f, 0.f};
        }
    }

    // ---- cross-lane argmin (over the 16 cols in each quad-group) ----
    #pragma unroll
    for (int mf = 0; mf < 4; mf++) {
        #pragma unroll
        for (int rg = 0; rg < 4; rg++) {
            float bv = rbv[mf][rg]; int bi = rbi[mf][rg];
            #pragma unroll
            for (int off = 1; off < 16; off <<= 1) {
                float ov = __shfl_xor(bv, off, 64);
                int   oi = __shfl_xor(bi, off, 64);
                if (ov < bv || (ov == bv && oi < bi)) { bv = ov; bi = oi; }
            }
            rbv[mf][rg] = bv; rbi[mf][rg] = bi;
        }
    }

    __syncthreads();   // all waves finished reading et
    float* sv = (float*)&et[0][0];   // 512 floats
    int*   si = (int*)(sv + 512);    // 512 ints
    if (col == 0) {
        #pragma unroll
        for (int mf = 0; mf < 4; mf++)
            #pragma unroll
            for (int rg = 0; rg < 4; rg++) {
                int rl = wm * 64 + mf * 16 + quad * 4 + rg;
                sv[wn * 128 + rl] = rbv[mf][rg];
                si[wn * 128 + rl] = rbi[mf][rg];
            }
    }
    __syncthreads();
    float myv = 0.f;
    if (tid < 128) {
        float bv = sv[tid]; int bi = si[tid];
        #pragma unroll
        for (int wnn = 1; wnn < 4; wnn++) {
            float ov = sv[wnn * 128 + tid]; int oi = si[wnn * 128 + tid];
            if (ov < bv || (ov == bv && oi < bi)) { bv = ov; bi = oi; }
        }
        g_idx[m0 + tid] = bi;
        atomicAdd(&hist[bi], 1);
        myv = bv;
    }
    #pragma unroll
    for (int off = 32; off; off >>= 1) myv += __shfl_down(myv, off, 64);
    if (lane == 0 && w < 2) atomicAdd(&sums[1], myv);
}

// ---------------- K3: loss + perplexity ----------------
__global__ void k_final(const int* __restrict__ hist,
                        const float* __restrict__ sums,
                        float* __restrict__ out_scalars) {
    __shared__ float red[4];
    const int tid = threadIdx.x;  // 256
    float s = 0.f;
    for (int i = tid; i < NE; i += 256) {
        float e = (float)hist[i] * (1.0f / 65536.0f);
        s += e * logf(e + 1e-10f);
    }
    #pragma unroll
    for (int off = 32; off; off >>= 1) s += __shfl_down(s, off, 64);
    if ((tid & 63) == 0) red[tid >> 6] = s;
    __syncthreads();
    if (tid == 0) {
        float total = red[0] + red[1] + red[2] + red[3];
        float perp = expf(-total);
        float loss = 1.25f * (sums[0] + sums[1]) / (65536.0f * 512.0f);
        out_scalars[0] = loss;
        out_scalars[1] = perp;
    }
}

// ---------------- K4: gather z_q[n][c][t] = emb[idx[m]][c] ----------------
__global__ void k_gather(const float* __restrict__ emb,
                         const int* __restrict__ idx,
                         float* __restrict__ out) {
    // grid: (8 t-chunks of 256, 32 n); 256 threads
    __shared__ int ids[256];
    const int n  = blockIdx.y;
    const int t0 = blockIdx.x * 256;
    const int tid = threadIdx.x;
    ids[tid] = idx[n * 2048 + t0 + tid];
    __syncthreads();
    const int tq = tid & 63;   // t group of 4
    const int cg = tid >> 6;   // 0..3
    const int i0 = ids[tq * 4 + 0];
    const int i1 = ids[tq * 4 + 1];
    const int i2 = ids[tq * 4 + 2];
    const int i3 = ids[tq * 4 + 3];
    const float* e0 = emb + (size_t)i0 * KD;
    const float* e1 = emb + (size_t)i1 * KD;
    const float* e2p = emb + (size_t)i2 * KD;
    const float* e3 = emb + (size_t)i3 * KD;
    for (int c = cg; c < KD; c += 4) {
        float4 o;
        o.x = e0[c]; o.y = e1[c]; o.z = e2p[c]; o.w = e3[c];
        *(float4*)(out + ((size_t)(n * KD + c)) * 2048 + t0 + tq * 4) = o;
    }
}

extern "C" void kernel_launch(void* const* d_in, const int* in_sizes, int n_in,
                              void* d_out, int out_size, void* d_ws, size_t ws_size,
                              hipStream_t stream) {
    (void)in_sizes; (void)n_in; (void)out_size; (void)ws_size;
    const float* z   = (const float*)d_in[0];   // 32*512*2048
    const float* emb = (const float*)d_in[1];   // 8192*512
    float* out = (float*)d_out;                 // 33554432 + 2
    char* ws = (char*)d_ws;

    float*          sums  = (float*)(ws + WS_SUMZ2);  // [0]=sumz2, [1]=sumsmin
    int*            hist  = (int*)(ws + WS_HIST);
    float*          e2    = (float*)(ws + WS_E2);
    int*            g_idx = (int*)(ws + WS_IDX);
    unsigned short* emb16 = (unsigned short*)(ws + WS_EMB16);
    unsigned short* z16   = (unsigned short*)(ws + WS_Z16);

    hipMemsetAsync(ws, 0, WS_ZEROSZ, stream);

    k_embprep<<<NE, 64, 0, stream>>>(emb, emb16, e2);
    k_zprep<<<dim3(32, 16, 32), 256, 0, stream>>>(z, z16, sums);
    k_main<<<512, 512, 0, stream>>>(z16, emb16, e2, g_idx, hist, sums);
    k_final<<<1, 256, 0, stream>>>(hist, sums, out + 33554432);
    k_gather<<<dim3(8, 32), 256, 0, stream>>>(emb, g_idx, out);
}

// Round 2
// 918.462 us; speedup vs baseline: 1.1692x; 1.1692x over previous
//
#include <hip/hip_runtime.h>
#include <stdint.h>

#define NE 8192
#define KD 512
#define MT 65536

typedef __attribute__((ext_vector_type(8))) short bf16x8;
typedef __attribute__((ext_vector_type(4))) float f32x4;

union U128 { uint4 u; bf16x8 b; };

// ---- workspace layout (bytes) ----
#define WS_SUMZ2   0                  // float
#define WS_SUMSMIN 4                  // float
#define WS_HIST    8                  // 8192 * int
#define WS_ZEROSZ  40960              // memset region covers the above
#define WS_E2      40960              // 8192 floats
#define WS_IDX     73728              // 65536 ints
#define WS_EMB16   335872             // 8192*512 bf16 (ushort)
#define WS_Z16     8724480            // 65536*512 bf16 (ushort)
// total ws needed: 75,833,344 bytes

__device__ __forceinline__ unsigned int f2bf(float f) {
    union { float f; unsigned int u; } c; c.f = f;
    return (c.u + 0x7FFFu + ((c.u >> 16) & 1u)) >> 16;
}

__device__ __forceinline__ void load_lds16(const void* g, void* l) {
    __builtin_amdgcn_global_load_lds((const __attribute__((address_space(1))) void*)g,
                                     (__attribute__((address_space(3))) void*)l,
                                     16, 0, 0);
}

// ---------------- K0: emb -> bf16, e2 = ||e||^2 ----------------
__global__ void k_embprep(const float* __restrict__ emb,
                          unsigned short* __restrict__ emb16,
                          float* __restrict__ e2) {
    const int code = blockIdx.x;
    const int lane = threadIdx.x;  // 64
    const float4* row = (const float4*)(emb + (size_t)code * KD);
    float4 a = row[lane * 2];
    float4 b = row[lane * 2 + 1];
    float s = a.x*a.x + a.y*a.y + a.z*a.z + a.w*a.w
            + b.x*b.x + b.y*b.y + b.z*b.z + b.w*b.w;
    uint4 o;
    o.x = f2bf(a.x) | (f2bf(a.y) << 16);
    o.y = f2bf(a.z) | (f2bf(a.w) << 16);
    o.z = f2bf(b.x) | (f2bf(b.y) << 16);
    o.w = f2bf(b.z) | (f2bf(b.w) << 16);
    ((uint4*)(emb16 + (size_t)code * KD))[lane] = o;
    #pragma unroll
    for (int off = 32; off; off >>= 1) s += __shfl_down(s, off, 64);
    if (lane == 0) e2[code] = s;
}

// ---------------- K1: transpose z (N,C,T) -> z16[M][K] bf16, sum z^2 ----------------
// LDS transpose: coalesced 256B loads along t, coalesced 128B-run uint4 stores along c.
__global__ void k_zprep(const float* __restrict__ z,
                        unsigned short* __restrict__ z16,
                        float* __restrict__ sumz2) {
    // grid: (32 t-tiles, 8 c-tiles, 32 n); 256 threads; tile = 64c x 64t
    __shared__ float arr[64][65];
    __shared__ float red[4];
    const int tid = threadIdx.x;
    const int n  = blockIdx.z;
    const int c0 = blockIdx.y * 64;
    const int t0 = blockIdx.x * 64;
    const int tl = tid & 63;
    const int cw = tid >> 6;  // 0..3
    const float* base = z + ((size_t)n * KD + c0) * 2048 + t0;
    float s = 0.f;
    #pragma unroll
    for (int u = 0; u < 16; u++) {
        int c = u * 4 + cw;
        float v = base[(size_t)c * 2048 + tl];
        arr[c][tl] = v;
        s += v * v;
    }
    #pragma unroll
    for (int off = 32; off; off >>= 1) s += __shfl_down(s, off, 64);
    if (tl == 0) red[cw] = s;
    __syncthreads();
    if (tid == 0) atomicAdd(sumz2, red[0] + red[1] + red[2] + red[3]);
    #pragma unroll
    for (int iter = 0; iter < 2; iter++) {
        int task = iter * 256 + tid;
        int row = task >> 3;       // t index 0..63
        int ch  = task & 7;        // uint4 chunk (8 c's)
        float f0 = arr[ch*8+0][row], f1 = arr[ch*8+1][row],
              f2v = arr[ch*8+2][row], f3 = arr[ch*8+3][row],
              f4 = arr[ch*8+4][row], f5 = arr[ch*8+5][row],
              f6 = arr[ch*8+6][row], f7 = arr[ch*8+7][row];
        uint4 o;
        o.x = f2bf(f0) | (f2bf(f1) << 16);
        o.y = f2bf(f2v) | (f2bf(f3) << 16);
        o.z = f2bf(f4) | (f2bf(f5) << 16);
        o.w = f2bf(f6) | (f2bf(f7) << 16);
        *(uint4*)(z16 + ((size_t)(n * 2048 + t0 + row)) * KD + c0 + ch * 8) = o;
    }
}

// ---------------- K2: fused GEMM + argmin ----------------
__global__ __launch_bounds__(512, 2) void k_main(
    const unsigned short* __restrict__ z16,   // [65536][512]
    const unsigned short* __restrict__ emb16, // [8192][512]
    const float* __restrict__ e2,             // [8192]
    int* __restrict__ g_idx,                  // [65536]
    int* __restrict__ hist,                   // [8192]
    float* __restrict__ sums)                 // ws base: [0]=sumz2, [1]=sumsmin
{
    __shared__ __align__(16) unsigned short zt[128 * 512];   // 131072 B, swizzled
    __shared__ __align__(16) unsigned short et[2][256 * 32]; // 32768 B, rot-swizzled

    const int tid  = threadIdx.x;
    const int lane = tid & 63;
    const int w    = tid >> 6;       // 0..7
    const int wm   = w & 1;
    const int wn   = w >> 1;         // 0..3
    const int quad = lane >> 4;
    const int col  = lane & 15;
    const int m0   = blockIdx.x * 128;

    // ---- stage zt: rows m0..m0+127, full K, 16B-chunk XOR swizzle ----
    {
        const int r  = tid >> 2;             // 0..127
        const int jb = (tid & 3) << 4;       // 0,16,32,48
        const uint4* gz = (const uint4*)(z16 + (size_t)(m0 + r) * KD);
        uint4* zt4w = (uint4*)zt;
        #pragma unroll
        for (int jj = 0; jj < 16; jj++) {
            int j  = jb + jj;
            int js = (j & 56) | ((j ^ r) & 7);
            zt4w[r * 64 + js] = gz[j];
        }
    }

    // staging address precompute: B chunk q of LDS-row n stored at n*4 + ((q + (n>>1))&3)
    // lds dst is linear (global_load_lds: base + lane*16); permute the global SOURCE column.
    const int st_nl0 = w * 16 + (lane >> 2);                 // row within 128-half
    const int st_q   = ((lane & 3) - ((st_nl0 >> 1) & 3)) & 3;
    const int st_q8  = st_q * 8;                             // source elem offset in K-slice
    unsigned short* st_l0 = &et[0][0] + w * 512 + lane * 8;          // p=0
    unsigned short* st_l1 = &et[0][0] + 4096 + w * 512 + lane * 8;   // p=1

    f32x4 acc[4][4];
    #pragma unroll
    for (int mf = 0; mf < 4; mf++)
        #pragma unroll
        for (int nf = 0; nf < 4; nf++)
            acc[mf][nf] = (f32x4){0.f, 0.f, 0.f, 0.f};

    float rbv[4][4]; int rbi[4][4];
    #pragma unroll
    for (int mf = 0; mf < 4; mf++)
        #pragma unroll
        for (int rg = 0; rg < 4; rg++) { rbv[mf][rg] = 3.0e38f; rbi[mf][rg] = 0; }

    // A-read precompute
    int zbase[4], r7[4];
    #pragma unroll
    for (int mf = 0; mf < 4; mf++) {
        int r = wm * 64 + mf * 16 + col;
        zbase[mf] = r * 64;
        r7[mf] = r & 7;
    }
    // B-read precompute (rotation swizzle: all 8 bank-quads covered per 16-lane phase)
    int bidx[4];
    #pragma unroll
    for (int nf = 0; nf < 4; nf++) {
        int nn = wn * 64 + nf * 16 + col;
        bidx[nf] = nn * 4 + ((quad + (nn >> 1)) & 3);
    }

    const uint4* zt4 = (const uint4*)zt;
    const uint4* et4[2] = { (const uint4*)&et[0][0], (const uint4*)&et[1][0] };

    // prologue: stage step 0 (chunk 0, kk 0 -> buf 0)
    {
        const unsigned short* g0 = emb16 + ((size_t)(st_nl0) << 9) + st_q8;
        const unsigned short* g1 = emb16 + ((size_t)(128 + st_nl0) << 9) + st_q8;
        load_lds16(g0, st_l0);
        load_lds16(g1, st_l1);
    }

    #pragma unroll 1
    for (int chunk = 0; chunk < 32; chunk++) {
        #pragma unroll
        for (int kk = 0; kk < 16; kk++) {
            __syncthreads();   // drains vmcnt: buf(kk&1) staged; prev reads of buf((kk+1)&1) done
            // prefetch next step into the other buffer
            const int nxt = chunk * 16 + kk + 1;
            if (nxt < 512) {
                const int nchunk = nxt >> 4, nkk = nxt & 15, nbuf = nxt & 1;
                const size_t koff = (size_t)nkk * 32 + st_q8;
                const unsigned short* g0 = emb16 + (((size_t)(nchunk * 256 + st_nl0)) << 9) + koff;
                const unsigned short* g1 = emb16 + (((size_t)(nchunk * 256 + 128 + st_nl0)) << 9) + koff;
                load_lds16(g0, st_l0 + nbuf * 8192);
                load_lds16(g1, st_l1 + nbuf * 8192);
            }
            const int buf = kk & 1;
            const int jhi  = (kk * 4) & 56;
            const int jlow = ((kk & 1) << 2) | quad;
            bf16x8 af[4], bfv[4];
            #pragma unroll
            for (int mf = 0; mf < 4; mf++) {
                U128 u; u.u = zt4[zbase[mf] + (jhi | (jlow ^ r7[mf]))];
                af[mf] = u.b;
            }
            #pragma unroll
            for (int nf = 0; nf < 4; nf++) {
                U128 u; u.u = et4[buf][bidx[nf]];
                bfv[nf] = u.b;
            }
            #pragma unroll
            for (int mf = 0; mf < 4; mf++)
                #pragma unroll
                for (int nf = 0; nf < 4; nf++)
                    acc[mf][nf] = __builtin_amdgcn_mfma_f32_16x16x32_bf16(
                        af[mf], bfv[nf], acc[mf][nf], 0, 0, 0);
        }
        // ---- epilogue: s = e2 - 2*dot, running argmin ----
        const int nb = chunk * 256 + wn * 64 + col;
        float e2v[4];
        #pragma unroll
        for (int nf = 0; nf < 4; nf++) e2v[nf] = e2[nb + nf * 16];
        #pragma unroll
        for (int mf = 0; mf < 4; mf++) {
            #pragma unroll
            for (int rg = 0; rg < 4; rg++) {
                float v0 = fmaf(-2.f, acc[mf][0][rg], e2v[0]);
                float v1 = fmaf(-2.f, acc[mf][1][rg], e2v[1]);
                float v2 = fmaf(-2.f, acc[mf][2][rg], e2v[2]);
                float v3 = fmaf(-2.f, acc[mf][3][rg], e2v[3]);
                float bv = v0; int bn = 0;
                if (v1 < bv) { bv = v1; bn = 1; }
                if (v2 < bv) { bv = v2; bn = 2; }
                if (v3 < bv) { bv = v3; bn = 3; }
                if (bv < rbv[mf][rg]) { rbv[mf][rg] = bv; rbi[mf][rg] = nb + (bn << 4); }
            }
            #pragma unroll
            for (int nf = 0; nf < 4; nf++)
                acc[mf][nf] = (f32x4){0.f, 0.f, 0.f, 0.f};
        }
    }

    // ---- cross-lane argmin (over the 16 cols in each quad-group) ----
    #pragma unroll
    for (int mf = 0; mf < 4; mf++) {
        #pragma unroll
        for (int rg = 0; rg < 4; rg++) {
            float bv = rbv[mf][rg]; int bi = rbi[mf][rg];
            #pragma unroll
            for (int off = 1; off < 16; off <<= 1) {
                float ov = __shfl_xor(bv, off, 64);
                int   oi = __shfl_xor(bi, off, 64);
                if (ov < bv || (ov == bv && oi < bi)) { bv = ov; bi = oi; }
            }
            rbv[mf][rg] = bv; rbi[mf][rg] = bi;
        }
    }

    __syncthreads();   // all waves finished reading et
    float* sv = (float*)&et[0][0];   // 512 floats
    int*   si = (int*)(sv + 512);    // 512 ints
    if (col == 0) {
        #pragma unroll
        for (int mf = 0; mf < 4; mf++)
            #pragma unroll
            for (int rg = 0; rg < 4; rg++) {
                int rl = wm * 64 + mf * 16 + quad * 4 + rg;
                sv[wn * 128 + rl] = rbv[mf][rg];
                si[wn * 128 + rl] = rbi[mf][rg];
            }
    }
    __syncthreads();
    float myv = 0.f;
    if (tid < 128) {
        float bv = sv[tid]; int bi = si[tid];
        #pragma unroll
        for (int wnn = 1; wnn < 4; wnn++) {
            float ov = sv[wnn * 128 + tid]; int oi = si[wnn * 128 + tid];
            if (ov < bv || (ov == bv && oi < bi)) { bv = ov; bi = oi; }
        }
        g_idx[m0 + tid] = bi;
        atomicAdd(&hist[bi], 1);
        myv = bv;
    }
    #pragma unroll
    for (int off = 32; off; off >>= 1) myv += __shfl_down(myv, off, 64);
    if (lane == 0 && w < 2) atomicAdd(&sums[1], myv);
}

// ---------------- K3: loss + perplexity ----------------
__global__ void k_final(const int* __restrict__ hist,
                        const float* __restrict__ sums,
                        float* __restrict__ out_scalars) {
    __shared__ float red[4];
    const int tid = threadIdx.x;  // 256
    float s = 0.f;
    for (int i = tid; i < NE; i += 256) {
        float e = (float)hist[i] * (1.0f / 65536.0f);
        s += e * logf(e + 1e-10f);
    }
    #pragma unroll
    for (int off = 32; off; off >>= 1) s += __shfl_down(s, off, 64);
    if ((tid & 63) == 0) red[tid >> 6] = s;
    __syncthreads();
    if (tid == 0) {
        float total = red[0] + red[1] + red[2] + red[3];
        float perp = expf(-total);
        float loss = 1.25f * (sums[0] + sums[1]) / (65536.0f * 512.0f);
        out_scalars[0] = loss;
        out_scalars[1] = perp;
    }
}

// ---------------- K4: gather z_q[n][c][t] = emb[idx[m]][c] ----------------
__global__ void k_gather(const float* __restrict__ emb,
                         const int* __restrict__ idx,
                         float* __restrict__ out) {
    // grid: (8 t-chunks of 256, 32 n); 256 threads
    __shared__ int ids[256];
    const int n  = blockIdx.y;
    const int t0 = blockIdx.x * 256;
    const int tid = threadIdx.x;
    ids[tid] = idx[n * 2048 + t0 + tid];
    __syncthreads();
    const int tq = tid & 63;   // t group of 4
    const int cg = tid >> 6;   // 0..3
    const float* e0 = emb + (size_t)ids[tq * 4 + 0] * KD;
    const float* e1 = emb + (size_t)ids[tq * 4 + 1] * KD;
    const float* e2p = emb + (size_t)ids[tq * 4 + 2] * KD;
    const float* e3 = emb + (size_t)ids[tq * 4 + 3] * KD;
    for (int cb = cg * 4; cb < KD; cb += 16) {
        float4 a = *(const float4*)(e0 + cb);
        float4 b = *(const float4*)(e1 + cb);
        float4 c = *(const float4*)(e2p + cb);
        float4 d = *(const float4*)(e3 + cb);
        float* op = out + ((size_t)(n * KD + cb)) * 2048 + t0 + tq * 4;
        float4 o0 = {a.x, b.x, c.x, d.x};
        float4 o1 = {a.y, b.y, c.y, d.y};
        float4 o2 = {a.z, b.z, c.z, d.z};
        float4 o3 = {a.w, b.w, c.w, d.w};
        *(float4*)(op)        = o0;
        *(float4*)(op + 2048) = o1;
        *(float4*)(op + 4096) = o2;
        *(float4*)(op + 6144) = o3;
    }
}

extern "C" void kernel_launch(void* const* d_in, const int* in_sizes, int n_in,
                              void* d_out, int out_size, void* d_ws, size_t ws_size,
                              hipStream_t stream) {
    (void)in_sizes; (void)n_in; (void)out_size; (void)ws_size;
    const float* z   = (const float*)d_in[0];   // 32*512*2048
    const float* emb = (const float*)d_in[1];   // 8192*512
    float* out = (float*)d_out;                 // 33554432 + 2
    char* ws = (char*)d_ws;

    float*          sums  = (float*)(ws + WS_SUMZ2);  // [0]=sumz2, [1]=sumsmin
    int*            hist  = (int*)(ws + WS_HIST);
    float*          e2    = (float*)(ws + WS_E2);
    int*            g_idx = (int*)(ws + WS_IDX);
    unsigned short* emb16 = (unsigned short*)(ws + WS_EMB16);
    unsigned short* z16   = (unsigned short*)(ws + WS_Z16);

    hipMemsetAsync(ws, 0, WS_ZEROSZ, stream);

    k_embprep<<<NE, 64, 0, stream>>>(emb, emb16, e2);
    k_zprep<<<dim3(32, 8, 32), 256, 0, stream>>>(z, z16, sums);
    k_main<<<512, 512, 0, stream>>>(z16, emb16, e2, g_idx, hist, sums);
    k_final<<<1, 256, 0, stream>>>(hist, sums, out + 33554432);
    k_gather<<<dim3(8, 32), 256, 0, stream>>>(emb, g_idx, out);
}